// Round 1
// baseline (457.418 us; speedup 1.0000x reference)
//
#include <hip/hip_runtime.h>
#include <hip/hip_bf16.h>

// Problem constants: B=8, N=256, H=128. M = B*N*N = 524288 rows.
// out[b,i,j,o] = (e[b,i,j,:] @ U_w^T)[o] + U_b[o] + Vx[b,i,o] + Vx[b,j,o]
// where Vx = x @ V_w^T + V_b.
// Strategy: vx2 = Vx + 0.5*U_b precomputed in d_ws (fp32), main GEMM in bf16
// MFMA (16x16x32), HBM-bound at ~512 MB traffic.

#define LDB 136  // padded bf16 leading dim for the 64x128 A tile (stride 272 B, 16B-aligned)

using bf16x8 = __attribute__((ext_vector_type(8))) short;
using f32x4  = __attribute__((ext_vector_type(4))) float;

__device__ inline bf16x8 pack8(const float4 a, const float4 b) {
  union { __hip_bfloat162 h2[4]; bf16x8 v; } u;
  u.h2[0] = __float22bfloat162_rn(make_float2(a.x, a.y));
  u.h2[1] = __float22bfloat162_rn(make_float2(a.z, a.w));
  u.h2[2] = __float22bfloat162_rn(make_float2(b.x, b.y));
  u.h2[3] = __float22bfloat162_rn(make_float2(b.z, b.w));
  return u.v;
}

// Kernel 1: vx2[r][o] = sum_h x[r][h]*V_w[o][h] + V_b[o] + 0.5*U_b[o]
// r in [0, 2048). 256 blocks x 256 threads; block handles 8 rows.
__global__ __launch_bounds__(256) void vx_kernel(
    const float* __restrict__ x, const float* __restrict__ Vw,
    const float* __restrict__ Vb, const float* __restrict__ Ub,
    float* __restrict__ vx2) {
  __shared__ float xs[8][128];
  const int r0 = blockIdx.x * 8;
  for (int i = threadIdx.x; i < 8 * 32; i += 256)
    ((float4*)&xs[0][0])[i] = ((const float4*)(x + (size_t)r0 * 128))[i];
  __syncthreads();

  const int o    = threadIdx.x & 127;
  const int half = threadIdx.x >> 7;  // rows half*4 .. half*4+3
  float acc[4] = {0.f, 0.f, 0.f, 0.f};
  const float4* vwrow = (const float4*)(Vw + (size_t)o * 128);
#pragma unroll 4
  for (int kc = 0; kc < 32; ++kc) {
    const float4 w4 = vwrow[kc];
#pragma unroll
    for (int r = 0; r < 4; ++r) {
      const float4 xv = ((const float4*)&xs[half * 4 + r][0])[kc];
      acc[r] += xv.x * w4.x + xv.y * w4.y + xv.z * w4.z + xv.w * w4.w;
    }
  }
  const float bias = Vb[o] + 0.5f * Ub[o];
#pragma unroll
  for (int r = 0; r < 4; ++r)
    vx2[(size_t)(r0 + half * 4 + r) * 128 + o] = acc[r] + bias;
}

// Kernel 2: the big row-GEMM + bias epilogue.
// Block = 256 threads = 4 waves. Wave w owns output cols [32w, 32w+32).
// B-fragments (U_w, bf16) live in registers, loaded once per block.
// Grid-stride loop over 8192 tiles of 64 rows; A tile staged fp32->bf16 in LDS.
__global__ __launch_bounds__(256) void edge_kernel(
    const float* __restrict__ e, const float* __restrict__ Uw,
    const float* __restrict__ vx2, float* __restrict__ out) {
  __shared__ alignas(16) __hip_bfloat16 As[64 * LDB];

  const int tid  = threadIdx.x;
  const int wave = tid >> 6;
  const int lane = tid & 63;
  const int ln   = lane & 15;  // MFMA n / m index
  const int kg   = lane >> 4;  // MFMA k-group (quad)

  // ---- B fragments: B[k][n] = Uw[n][k]; lane needs Uw[o][kg*8 + j], j=0..7
  bf16x8 bfrag[2][4];
#pragma unroll
  for (int c = 0; c < 2; ++c) {
    const int o = 32 * wave + 16 * c + ln;
#pragma unroll
    for (int ks = 0; ks < 4; ++ks) {
      const float4* p = (const float4*)(Uw + (size_t)o * 128 + kg * 8 + ks * 32);
      bfrag[c][ks] = pack8(p[0], p[1]);
    }
  }

  const int nTiles = (8 * 256 * 256) / 64;  // 8192
  for (int t = blockIdx.x; t < nTiles; t += gridDim.x) {
    const size_t rowBase = (size_t)t * 64;

    // ---- stage: 64 rows x 128 cols fp32 -> bf16 LDS, fully coalesced loads
    {
      const float4* src = (const float4*)(e + rowBase * 128);
      float4 f[8];
#pragma unroll
      for (int i = 0; i < 8; ++i) f[i] = src[i * 256 + tid];
#pragma unroll
      for (int i = 0; i < 8; ++i) {
        const int fi  = i * 256 + tid;
        const int row = fi >> 5;         // 4 floats per f4, 32 f4 per row
        const int col = (fi & 31) * 4;
        union { __hip_bfloat162 h2[2]; unsigned long long u; } p;
        p.h2[0] = __float22bfloat162_rn(make_float2(f[i].x, f[i].y));
        p.h2[1] = __float22bfloat162_rn(make_float2(f[i].z, f[i].w));
        *(unsigned long long*)&As[row * LDB + col] = p.u;
      }
    }
    __syncthreads();

    // ---- compute: 4 row sub-tiles x 2 col tiles, K=128 in 4 MFMA steps
    f32x4 acc[4][2];
#pragma unroll
    for (int sub = 0; sub < 4; ++sub) {
      bf16x8 afrag[4];
#pragma unroll
      for (int ks = 0; ks < 4; ++ks)
        afrag[ks] = *(const bf16x8*)&As[(sub * 16 + ln) * LDB + kg * 8 + ks * 32];
#pragma unroll
      for (int c = 0; c < 2; ++c) {
        f32x4 a = {0.f, 0.f, 0.f, 0.f};
#pragma unroll
        for (int ks = 0; ks < 4; ++ks)
          a = __builtin_amdgcn_mfma_f32_16x16x32_bf16(afrag[ks], bfrag[c][ks], a, 0, 0, 0);
        acc[sub][c] = a;
      }
    }

    // ---- epilogue: out = acc + vx2[b*256+i] + vx2[b*256+j]
    // C/D layout: col = ln, row = kg*4 + reg
#pragma unroll
    for (int sub = 0; sub < 4; ++sub) {
      const size_t rsub = rowBase + sub * 16;
      const int bi = (int)(rsub >> 8);            // b*256 + i (const per sub-tile)
      const int b_ = (int)(rsub >> 16);           // b
      const int j0 = (int)(rsub & 255);           // j of first row in sub-tile
      const int jr = b_ * 256 + j0;               // vx2 row base for j
#pragma unroll
      for (int c = 0; c < 2; ++c) {
        const int o = 32 * wave + 16 * c + ln;
        const float vxi = vx2[(size_t)bi * 128 + o];
#pragma unroll
        for (int reg = 0; reg < 4; ++reg) {
          const int rr = kg * 4 + reg;
          const float vxj = vx2[(size_t)(jr + rr) * 128 + o];
          out[(rsub + rr) * 128 + o] = acc[sub][c][reg] + vxi + vxj;
        }
      }
    }
    __syncthreads();  // protect As before next tile's staging writes
  }
}

extern "C" void kernel_launch(void* const* d_in, const int* in_sizes, int n_in,
                              void* d_out, int out_size, void* d_ws, size_t ws_size,
                              hipStream_t stream) {
  // setup_inputs order: x, e, U_w, U_b, V_w, V_b (all fp32)
  const float* x  = (const float*)d_in[0];
  const float* e  = (const float*)d_in[1];
  const float* Uw = (const float*)d_in[2];
  const float* Ub = (const float*)d_in[3];
  const float* Vw = (const float*)d_in[4];
  const float* Vb = (const float*)d_in[5];
  float* out = (float*)d_out;
  float* vx2 = (float*)d_ws;  // needs 2048*128*4 = 1 MB of scratch

  vx_kernel<<<256, 256, 0, stream>>>(x, Vw, Vb, Ub, vx2);
  edge_kernel<<<2048, 256, 0, stream>>>(e, Uw, vx2, out);
}